// Round 2
// baseline (868.894 us; speedup 1.0000x reference)
//
#include <hip/hip_runtime.h>

// Pooler: bilinear ROI grid-sample. B=4,C=256,H=256,W=512, 400 ROIs, 14x14 grid.
// Strategy: one block per (n,c). Since x-sample spacing = bw/52 floats <= 15.4 < 16,
// every 64B line in the row span is touched anyway -> stage full contiguous row
// spans into LDS with coalesced float4 loads (same HBM traffic as scattered
// gathers, far better VMEM efficiency), then interpolate from LDS.
constexpr int B = 4, C = 256, H = 256, W = 512;
constexpr int MAXLOAD = 100, FS = 14;
constexpr int NROI = B * MAXLOAD;        // 400
constexpr int HB = B * H;                // 1024 flattened rows
constexpr int MAIN = NROI * C * FS * FS; // 20,070,400
constexpr int NROWS = 2 * FS;            // 14 y0-rows + 14 y1-rows (dupes ok, L2-hot)
constexpr int STRIDE = 212;              // LDS row stride in floats (mult of 4; 212%32=20)
// max span: bw<=800 -> scalex/4*(512/511) ~ 200.4 floats; +1 (x1) +3 (align) = 205 <= 212. ok.

__global__ __launch_bounds__(256) void pooler_stage_kernel(
    const float* __restrict__ feats,   // (B,C,H,W) fp32
    const float* __restrict__ rois,    // (400,4)
    float* __restrict__ out)           // (400,C,14,14) ++ val_bind(400)
{
    __shared__ float buf[NROWS * STRIDE];

    const int blk = blockIdx.x;          // n*256 + c  (n-major: same-batch ROIs concurrent -> L3 reuse)
    const int c   = blk & (C - 1);
    const int n   = blk >> 8;
    const int vb  = n / MAXLOAD;
    const int tid = threadIdx.x;

    const float4 roi = reinterpret_cast<const float4*>(rois)[n];
    const float scalex = roi.z - roi.x;
    const float scaley = roi.w - roi.y;
    const float biasx  = roi.x;
    const float biasy  = roi.y + (float)vb * 1024.0f;   // image_height=1024

    // px = ((fx/13*scalex + biasx)/4) * W/(W-1) - 0.5, clip [0,511]
    // py = ((fy/13*scaley + biasy)/4) * HB/(HB-1) - 0.5, clip [0,1023]
    // (identical fp sequence used in staging and compute phases -> consistent x0/y0)
    auto PX = [&](int fx) {
        float g = ((float)fx * (1.0f / 13.0f) * scalex + biasx) * 0.25f;
        float p = g * (512.0f / 511.0f) - 0.5f;
        return fminf(fmaxf(p, 0.0f), 511.0f);
    };
    auto PY = [&](int fy) {
        float g = ((float)fy * (1.0f / 13.0f) * scaley + biasy) * 0.25f;
        float p = g * (1024.0f / 1023.0f) - 0.5f;
        return fminf(fmaxf(p, 0.0f), 1023.0f);
    };

    // x-span (monotonic in fx since scalex > 0)
    const int x_lo  = (int)floorf(PX(0));
    const int x_hi  = min((int)floorf(PX(13)) + 1, W - 1);
    const int xbase = x_lo & ~3;                 // float4-aligned start
    const int span4 = ((x_hi - xbase) >> 2) + 1; // float4s per row (2..52)
    const int total = NROWS * span4;
    const int cb    = c * (H * W);

    // ---- stage 28 row spans into LDS (coalesced float4) ----
    for (int t = tid; t < total; t += 256) {
        int i  = t / span4;
        int j  = t - i * span4;
        int fy = (i < FS) ? i : i - FS;
        int y0 = (int)floorf(PY(fy));
        int y  = (i < FS) ? y0 : min(y0 + 1, HB - 1);   // y1 may cross batch row — matches ref
        int rowbase = ((y >> 8) * (C * H) + (y & (H - 1))) * W + cb;
        int col = xbase + (j << 2);
        float4 v;
        if (col + 3 < W) {
            v = *reinterpret_cast<const float4*>(feats + rowbase + col);
        } else {                                  // row-edge tail: clamp, avoid OOB
            v.x = feats[rowbase + min(col,     W - 1)];
            v.y = feats[rowbase + min(col + 1, W - 1)];
            v.z = feats[rowbase + min(col + 2, W - 1)];
            v.w = feats[rowbase + min(col + 3, W - 1)];
        }
        *reinterpret_cast<float4*>(&buf[i * STRIDE + (j << 2)]) = v;
    }

    __syncthreads();

    // ---- 196 outputs from LDS ----
    if (tid < FS * FS) {
        int fx = tid % FS;
        int fy = tid / FS;
        float px = PX(fx);
        float py = PY(fy);
        float x0f = floorf(px), y0f = floorf(py);
        float wx = px - x0f,   wy = py - y0f;
        int x0 = (int)x0f - xbase;
        int x1 = min((int)x0f + 1, W - 1) - xbase;
        const float* r0 = &buf[fy * STRIDE];
        const float* r1 = &buf[(fy + FS) * STRIDE];
        float f00 = r0[x0], f01 = r0[x1];
        float f10 = r1[x0], f11 = r1[x1];
        float v0 = f00 + wx * (f01 - f00);
        float v1 = f10 + wx * (f11 - f10);
        out[(size_t)blk * (FS * FS) + tid] = v0 + wy * (v1 - v0);
    } else if (c == 0 && tid == 255) {
        out[MAIN + n] = (float)vb;               // val_bind tail as fp32
    }
}

extern "C" void kernel_launch(void* const* d_in, const int* in_sizes, int n_in,
                              void* d_out, int out_size, void* d_ws, size_t ws_size,
                              hipStream_t stream) {
    const float* feats = (const float*)d_in[0];
    const float* rois  = (const float*)d_in[1];
    float* out = (float*)d_out;

    pooler_stage_kernel<<<NROI * C, 256, 0, stream>>>(feats, rois, out);
}